// Round 9
// baseline (528.512 us; speedup 1.0000x reference)
//
#include <hip/hip_runtime.h>
#include <hip/hip_bf16.h>

typedef _Float16 half8 __attribute__((ext_vector_type(8)));
typedef float f32x4 __attribute__((ext_vector_type(4)));

#define Bsz 32
#define Nseq 2048
#define Edim 1024
#define Hdim 1024

// async global->LDS, 16B per lane. LDS dest = wave-uniform base + lane*16;
// swizzled layouts are achieved by pre-swizzling the per-lane GLOBAL source
// (m173 / rule #21), LDS dest stays linear.
__device__ __forceinline__ void gload_lds16(const void* g, void* l) {
    __builtin_amdgcn_global_load_lds(
        (const __attribute__((address_space(1))) unsigned int*)g,
        (__attribute__((address_space(3))) unsigned int*)l, 16, 0, 0);
}

// ---------------- kernel 1a: dw[b,h] = dec[b,:] @ w_d[:,h]  (f32) ------------
__global__ void k_dw(const float* __restrict__ dec, const float* __restrict__ w_d,
                     float* __restrict__ dw) {
    int b = blockIdx.x;
    int h = blockIdx.y * 256 + threadIdx.x;
    const float* dr = dec + b * 1024;
    float a0 = 0.f, a1 = 0.f, a2 = 0.f, a3 = 0.f;
    for (int d = 0; d < 1024; d += 4) {
        a0 += dr[d + 0] * w_d[(d + 0) * 1024 + h];
        a1 += dr[d + 1] * w_d[(d + 1) * 1024 + h];
        a2 += dr[d + 2] * w_d[(d + 2) * 1024 + h];
        a3 += dr[d + 3] * w_d[(d + 3) * 1024 + h];
    }
    dw[b * 1024 + h] = (a0 + a1) + (a2 + a3);
}

// ------- kernel 1b: split w_e (f32 [E][H]) into fp16 hi/lo, transposed [H][E] -
__global__ void k_split(const float* __restrict__ w_e,
                        _Float16* __restrict__ w_hiT, _Float16* __restrict__ w_loT) {
    __shared__ _Float16 th[32][33];
    __shared__ _Float16 tl[32][33];
    int e0 = blockIdx.x * 32, h0 = blockIdx.y * 32;
    int tx = threadIdx.x & 31, ty = threadIdx.x >> 5;
#pragma unroll
    for (int i = 0; i < 4; ++i) {
        int r = ty + i * 8;
        float x = w_e[(size_t)(e0 + r) * 1024 + h0 + tx];
        _Float16 h = (_Float16)x;
        th[r][tx] = h;
        tl[r][tx] = (_Float16)(x - (float)h);
    }
    __syncthreads();
#pragma unroll
    for (int i = 0; i < 4; ++i) {
        int r = ty + i * 8;
        w_hiT[(size_t)(h0 + r) * 1024 + e0 + tx] = th[tx][r];
        w_loT[(size_t)(h0 + r) * 1024 + e0 + tx] = tl[tx][r];
    }
}

// ---------------- kernel 2: scores[m] = sum_h w_out[h]*tanh((enc@w_e)[m,h]+dw[b,h])
// fp16x3 split MFMA, 16x16x32. 512 thr (8 waves, 2x4), M_TILE=256, H_CHUNK=256,
// K_STEP=32, flat tile loop t=0..127 (hc=t>>5, kt=t&31). Grid 256 = 1 block/CU.
//
// r8 change (work content, not schedule - r7 vs r8 proved phases are not the
// limiter): ALL staging is async global_load_lds (A as raw f32; zero staging
// VALU, zero ds_write, no pa regs). Waves convert A f32->fp16 hi/lo JIT
// in-register per m-fragment. XOR-swizzled LDS (T2, both-sides: pre-swizzled
// global source + swizzled read offsets; linear DMA dest):
//   A: byte = ks*8192 + ((row^ks)*32) + half*16       ([4ks][256r][32B f32])
//   B: byte = ks*4096 + ((r^(2ks))*16)                ([4ks][256r][16B] hi, +16384 lo)
// kills the constant 2.5e7 bank-conflict floor (ks-planes were bank-aligned:
// 8-way B-read conflicts in r4-r8).
//
// Dynamic LDS 132096 B:
//   A buf0/1: 0 / 32768 (f32)    B buf0/1: 65536 / 98304 (hi 16K + lo 16K)
//   scoreL: 131072 (256 f32)
__global__ __launch_bounds__(512, 2)
void k_scores(const float* __restrict__ enc,
              const _Float16* __restrict__ w_hiT, const _Float16* __restrict__ w_loT,
              const float* __restrict__ dw, const float* __restrict__ w_out,
              float* __restrict__ scores) {
    extern __shared__ __align__(16) char smem[];
    float* scoreL = (float*)(smem + 131072);

    const int tid  = threadIdx.x;
    const int lane = tid & 63;
    const int wave = tid >> 6;
    const int wr = wave >> 2, wc = wave & 3;     // 2 x 4 wave grid
    const int m0 = blockIdx.x * 256;
    const int bb = m0 >> 11;
    const float* dwb = dw + bb * 1024;
    const int rb = lane & 15, ksl = lane >> 4;

    const char* encB = (const char*)enc + (size_t)m0 * 4096;
    const char* whiB = (const char*)w_hiT;
    const char* wloB = (const char*)w_loT;

    // per-lane swizzled READ bases (+ compile-time offsets at use sites)
    const int aAddr = ksl * 8192 + ((rb ^ ksl) << 5) + wr * 4096;  // + m*512 (+16)
    const int bAddr = ksl * 4096 + ((rb ^ (2 * ksl)) << 4) + wc * 1024;  // + n*256; lo +16384

    if (tid < 256) scoreL[tid] = 0.f;

    f32x4 acc[8][4];
#pragma unroll
    for (int m = 0; m < 8; ++m)
#pragma unroll
        for (int n = 0; n < 4; ++n) acc[m][n] = (f32x4){0.f, 0.f, 0.f, 0.f};

// A: instr k writes plane k; lane tid -> LDS byte k*8192 + tid*16.
// content: row=(tid>>1)^k (inverse swizzle), half=tid&1, k-seg k.
#define A_ISSUE(t, buf) do { \
        const int _kt = (t) & 31; \
        char* _d = smem + (buf) * 32768; \
        _Pragma("unroll") \
        for (int _k = 0; _k < 4; ++_k) { \
            const char* _s = encB + (size_t)((tid >> 1) ^ _k) * 4096 \
                           + (size_t)_kt * 128 + _k * 32 + (tid & 1) * 16; \
            gload_lds16(_s, _d + _k * 8192 + tid * 16); \
        } \
    } while (0)
// B: instr j covers planes ks=2j+(tid>>8); content row r=(tid&255)^(2ks).
#define B_ISSUE(t, buf) do { \
        const int _kt = (t) & 31; \
        const size_t _h0 = (size_t)((t) >> 5) << 19; \
        char* _d = smem + 65536 + (buf) * 32768; \
        _Pragma("unroll") \
        for (int _j = 0; _j < 2; ++_j) { \
            const int _ks = 2 * _j + (tid >> 8); \
            const size_t _ro = _h0 + (size_t)((tid & 255) ^ (2 * _ks)) * 2048 \
                             + (size_t)_kt * 64 + _ks * 16; \
            gload_lds16(whiB + _ro, _d + _j * 8192 + tid * 16); \
            gload_lds16(wloB + _ro, _d + 16384 + _j * 8192 + tid * 16); \
        } \
    } while (0)

    // prologue: stage tile 0 into buf0
    A_ISSUE(0, 0);
    B_ISSUE(0, 0);
    __syncthreads();   // implicit vmcnt(0): tile 0 landed

    for (int t = 0; t < 128; ++t) {
        const int cur = t & 1;
        if (t < 127) {             // 8 async DMA issues, land under this tile's work
            A_ISSUE(t + 1, cur ^ 1);
            B_ISSUE(t + 1, cur ^ 1);
        }
        const char* sa = smem + cur * 32768;
        const char* sb = smem + 65536 + cur * 32768;

        half8 bh[4], bl[4];
#pragma unroll
        for (int n = 0; n < 4; ++n) {
            bh[n] = *(const half8*)(sb + bAddr + n * 256);
            bl[n] = *(const half8*)(sb + 16384 + bAddr + n * 256);
        }
#pragma unroll
        for (int m = 0; m < 8; ++m) {
            // JIT convert: 8 f32 -> hi/lo fp16 (fp16x3 numerics unchanged)
            f32x4 q0 = *(const f32x4*)(sa + aAddr + m * 512);
            f32x4 q1 = *(const f32x4*)(sa + aAddr + m * 512 + 16);
            half8 ah, al;
#pragma unroll
            for (int j = 0; j < 4; ++j) {
                float v0 = q0[j], v1 = q1[j];
                _Float16 h0 = (_Float16)v0;
                ah[j] = h0;
                al[j] = (_Float16)(v0 - (float)h0);
                _Float16 h1 = (_Float16)v1;
                ah[j + 4] = h1;
                al[j + 4] = (_Float16)(v1 - (float)h1);
            }
#pragma unroll
            for (int n = 0; n < 4; ++n) {
                acc[m][n] = __builtin_amdgcn_mfma_f32_16x16x32_f16(ah, bh[n], acc[m][n], 0, 0, 0);
                acc[m][n] = __builtin_amdgcn_mfma_f32_16x16x32_f16(ah, bl[n], acc[m][n], 0, 0, 0);
                acc[m][n] = __builtin_amdgcn_mfma_f32_16x16x32_f16(al, bh[n], acc[m][n], 0, 0, 0);
            }
        }

        if ((t & 31) == 31) {
            // epilogue for hc = t>>5: branch-free tanh + w_out, reduce, atomic
            const int h0 = (t >> 5) << 8;
#pragma unroll
            for (int m = 0; m < 8; ++m) {
                float con[4] = {0.f, 0.f, 0.f, 0.f};
#pragma unroll
                for (int n = 0; n < 4; ++n) {
                    int h = h0 + wc * 64 + n * 16 + rb;
                    float dwv = dwb[h];
                    float wo  = w_out[h];
#pragma unroll
                    for (int r = 0; r < 4; ++r) {
                        float x = acc[m][n][r] + dwv;
                        float e = __expf(2.0f * fabsf(x));
                        float th = copysignf(1.0f - __fdividef(2.0f, e + 1.0f), x);
                        con[r] += th * wo;
                    }
                    acc[m][n] = (f32x4){0.f, 0.f, 0.f, 0.f};
                }
#pragma unroll
                for (int r = 0; r < 4; ++r) {
                    float v = con[r];
                    v += __shfl_xor(v, 1);
                    v += __shfl_xor(v, 2);
                    v += __shfl_xor(v, 4);
                    v += __shfl_xor(v, 8);
                    con[r] = v;
                }
                if (rb == 0) {
                    int rbase = wr * 128 + m * 16 + ksl * 4;
#pragma unroll
                    for (int r = 0; r < 4; ++r)
                        atomicAdd(&scoreL[rbase + r], con[r]);
                }
            }
        }
        __syncthreads();   // drain vm+lgkm: tile t+1 fully staged; cur freed
    }

    __syncthreads();
    if (tid < 256) scores[m0 + tid] = scoreL[tid];
#undef A_ISSUE
#undef B_ISSUE
}

// ---------------- kernel 3: masked softmax over N per batch ----------------
// mask is bool in python -> pushed as int32.
__global__ void k_softmax(const float* __restrict__ scores,
                          const int* __restrict__ mask,
                          float* __restrict__ probs, float* __restrict__ out_probs) {
    int b = blockIdx.x, tid = threadIdx.x;
    __shared__ float red[8];
    float v[8];
    float m = -INFINITY;
#pragma unroll
    for (int i = 0; i < 8; ++i) {
        int n = tid + i * 256;
        float s = scores[b * 2048 + n];
        s = (mask[b * 2048 + n] != 0) ? s : -INFINITY;
        v[i] = s;
        m = fmaxf(m, s);
    }
    for (int off = 32; off; off >>= 1) m = fmaxf(m, __shfl_xor(m, off));
    if ((tid & 63) == 0) red[tid >> 6] = m;
    __syncthreads();
    m = fmaxf(fmaxf(red[0], red[1]), fmaxf(red[2], red[3]));
    float sum = 0.f;
#pragma unroll
    for (int i = 0; i < 8; ++i) {
        v[i] = expf(v[i] - m);
        sum += v[i];
    }
    for (int off = 32; off; off >>= 1) sum += __shfl_xor(sum, off);
    if ((tid & 63) == 0) red[4 + (tid >> 6)] = sum;
    __syncthreads();
    sum = red[4] + red[5] + red[6] + red[7];
    float inv = 1.0f / sum;
#pragma unroll
    for (int i = 0; i < 8; ++i) {
        int n = tid + i * 256;
        float p = v[i] * inv;
        probs[b * 2048 + n]     = p;
        out_probs[b * 2048 + n] = p;
    }
}

// ---------------- kernel 4: attn[b,e] += sum_n probs[b,n]*enc[b,n,e] --------
// Survivor compaction (softmax is near-one-hot), then unconditional FMA loop.
__global__ void k_attn(const float* __restrict__ probs, const float* __restrict__ enc,
                       float* __restrict__ attn) {
    __shared__ float pv[128];
    __shared__ int   pidx[128];
    __shared__ int   cnt;
    int b = blockIdx.x, c = blockIdx.y, t = threadIdx.x;
    if (t == 0) cnt = 0;
    __syncthreads();
    if (t < 128) {
        float p = probs[b * 2048 + c * 128 + t];
        if (p >= 1e-12f) {
            int slot = atomicAdd(&cnt, 1);
            pv[slot]   = p;
            pidx[slot] = c * 128 + t;
        }
    }
    __syncthreads();
    int nk = cnt;
    if (nk == 0) return;
    const float* eb = enc + (size_t)b * 2048 * 1024;
    float4 acc = {0.f, 0.f, 0.f, 0.f};
    for (int i = 0; i < nk; ++i) {
        float p = pv[i];
        float4 v = ((const float4*)(eb + (size_t)pidx[i] * 1024))[t];
        acc.x += p * v.x;
        acc.y += p * v.y;
        acc.z += p * v.z;
        acc.w += p * v.w;
    }
    float* o = attn + b * 1024 + t * 4;
    atomicAdd(o + 0, acc.x);
    atomicAdd(o + 1, acc.y);
    atomicAdd(o + 2, acc.z);
    atomicAdd(o + 3, acc.w);
}

extern "C" void kernel_launch(void* const* d_in, const int* in_sizes, int n_in,
                              void* d_out, int out_size, void* d_ws, size_t ws_size,
                              hipStream_t stream) {
    const float* enc   = (const float*)d_in[0];  // [32,2048,1024]
    const float* dec   = (const float*)d_in[1];  // [32,1024]
    const int*   mask  = (const int*)d_in[2];    // [32,2048] bool -> int32
    const float* w_e   = (const float*)d_in[3];  // [1024,1024]
    const float* w_d   = (const float*)d_in[4];  // [1024,1024]
    const float* w_out = (const float*)d_in[5];  // [1024]

    float* out_attn  = (float*)d_out;              // [32*1024]
    float* out_probs = out_attn + Bsz * Hdim;      // [32*2048]

    float* dw        = (float*)d_ws;               // 32*1024
    float* scores    = dw + Bsz * Hdim;            // 32*2048
    float* probs     = scores + Bsz * Nseq;        // 32*2048
    _Float16* w_hiT  = (_Float16*)(probs + Bsz * Nseq);  // [1024*1024]
    _Float16* w_loT  = w_hiT + Edim * Hdim;

    static const int kScoresLds = 132096;   // 128 KB bufs + 1 KB scoreL
    hipFuncSetAttribute((const void*)k_scores,
                        hipFuncAttributeMaxDynamicSharedMemorySize, kScoresLds);

    hipMemsetAsync(out_attn, 0, Bsz * Hdim * sizeof(float), stream);
    k_dw<<<dim3(32, 4), dim3(256), 0, stream>>>(dec, w_d, dw);
    k_split<<<dim3(32, 32), dim3(256), 0, stream>>>(w_e, w_hiT, w_loT);
    k_scores<<<dim3(256), dim3(512), kScoresLds, stream>>>(enc, w_hiT, w_loT, dw, w_out, scores);
    k_softmax<<<dim3(32), dim3(256), 0, stream>>>(scores, mask, probs, out_probs);
    k_attn<<<dim3(32, 16), dim3(256), 0, stream>>>(probs, enc, out_attn);
}

// Round 10
// 440.142 us; speedup vs baseline: 1.2008x; 1.2008x over previous
//
#include <hip/hip_runtime.h>
#include <hip/hip_bf16.h>

typedef _Float16 half8 __attribute__((ext_vector_type(8)));
typedef float f32x4 __attribute__((ext_vector_type(4)));

#define Bsz 32
#define Nseq 2048
#define Edim 1024
#define Hdim 1024

// async global->LDS, 16B per lane. LDS dest = wave-uniform base + lane*16;
// swizzled layouts via pre-swizzled per-lane GLOBAL source (rule #21).
__device__ __forceinline__ void gload_lds16(const void* g, void* l) {
    __builtin_amdgcn_global_load_lds(
        (const __attribute__((address_space(1))) unsigned int*)g,
        (__attribute__((address_space(3))) unsigned int*)l, 16, 0, 0);
}

// ---------------- kernel 1a: dw[b,h] = dec[b,:] @ w_d[:,h]  (f32) ------------
__global__ void k_dw(const float* __restrict__ dec, const float* __restrict__ w_d,
                     float* __restrict__ dw) {
    int b = blockIdx.x;
    int h = blockIdx.y * 256 + threadIdx.x;
    const float* dr = dec + b * 1024;
    float a0 = 0.f, a1 = 0.f, a2 = 0.f, a3 = 0.f;
    for (int d = 0; d < 1024; d += 4) {
        a0 += dr[d + 0] * w_d[(d + 0) * 1024 + h];
        a1 += dr[d + 1] * w_d[(d + 1) * 1024 + h];
        a2 += dr[d + 2] * w_d[(d + 2) * 1024 + h];
        a3 += dr[d + 3] * w_d[(d + 3) * 1024 + h];
    }
    dw[b * 1024 + h] = (a0 + a1) + (a2 + a3);
}

// ------- kernel 1b: split w_e (f32 [E][H]) into fp16 hi/lo, transposed [H][E] -
__global__ void k_split(const float* __restrict__ w_e,
                        _Float16* __restrict__ w_hiT, _Float16* __restrict__ w_loT) {
    __shared__ _Float16 th[32][33];
    __shared__ _Float16 tl[32][33];
    int e0 = blockIdx.x * 32, h0 = blockIdx.y * 32;
    int tx = threadIdx.x & 31, ty = threadIdx.x >> 5;
#pragma unroll
    for (int i = 0; i < 4; ++i) {
        int r = ty + i * 8;
        float x = w_e[(size_t)(e0 + r) * 1024 + h0 + tx];
        _Float16 h = (_Float16)x;
        th[r][tx] = h;
        tl[r][tx] = (_Float16)(x - (float)h);
    }
    __syncthreads();
#pragma unroll
    for (int i = 0; i < 4; ++i) {
        int r = ty + i * 8;
        w_hiT[(size_t)(h0 + r) * 1024 + e0 + tx] = th[tx][r];
        w_loT[(size_t)(h0 + r) * 1024 + e0 + tx] = tl[tx][r];
    }
}

// ---------------- kernel 2: scores[m] = sum_h w_out[h]*tanh((enc@w_e)[m,h]+dw[b,h])
// fp16x3 split MFMA, 16x16x32. 512 thr (8 waves, 2x4), M_TILE=256, H_CHUNK=256,
// K_STEP=32, 128 K-tiles, r7's 4-phase counted-vmcnt schedule.
//
// r10 change vs r7 (ONE variable): correct stripe-XOR LDS swizzle (T2).
// Tiles (A hi/lo, B hi/lo: each 256 rows x 64 B) stored as 128B row-pair
// stripes with chunk XOR:
//   byte(row, d) = (row>>1)*128 + (row&1)*64 + ((d ^ ((row>>1)&3))<<4)
// Read slot = (row&1)*4 + d^((row>>1)&3): 16 frag-lanes -> 8 slots = 2-way
// (free, m136). r7-r9's 64B-row layouts were inherently 8-way (16B stride
// covers only 8 bank-slots). A: swizzled ds_write (reg-staged, converts once).
// B: DMA with pre-swizzled global source (XOR is an involution).
//
// Dynamic LDS 132096 B (1 block/CU):
//   A buf0/1 @0/32768 (hi 16K + lo 16K)   B buf0/1 @65536/98304 (hi+lo)
//   scoreL @131072 (256 f32)
__global__ __launch_bounds__(512, 2)
void k_scores(const float* __restrict__ enc,
              const _Float16* __restrict__ w_hiT, const _Float16* __restrict__ w_loT,
              const float* __restrict__ dw, const float* __restrict__ w_out,
              float* __restrict__ scores) {
    extern __shared__ __align__(16) char smem[];
    float* scoreL = (float*)(smem + 131072);

    const int tid  = threadIdx.x;
    const int lane = tid & 63;
    const int wave = tid >> 6;
    const int wr = wave >> 2, wc = wave & 3;     // 2 x 4 wave grid
    const int m0 = blockIdx.x * 256;
    const int bb = m0 >> 11;
    const float* dwb = dw + bb * 1024;
    const int rb = lane & 15, ksl = lane >> 4;

    // A raw staging coords: thread loads rows a_row, a_row+128 at kseg a_ks
    const int a_row = tid >> 2, a_ks = tid & 3;
    const float* aBase = enc + (size_t)(m0 + a_row) * 1024 + a_ks * 8;
    // A swizzled ds_write base (chunk XOR is row-pair dependent)
    const int aWofs = (a_row >> 1) * 128 + (a_row & 1) * 64
                    + ((a_ks ^ ((a_row >> 1) & 3)) << 4);   // row+128: same (p&3)
    // B DMA: per-thread pre-swizzled source decode (dest = linear tid*16)
    const int bRow0 = 2 * (tid >> 3) + ((tid >> 2) & 1);    // j=1 adds 128
    const int bD    = ((tid & 3) ^ ((tid >> 3) & 3)) << 4;  // swizzled k-chunk byte
    const char* whiB = (const char*)w_hiT;
    const char* wloB = (const char*)w_loT;

    // fragment read bases: (row>>1)&3 == (rb>>1)&3 for all m/n offsets
    const int p2 = rb >> 1;
    const int swz = (ksl ^ (p2 & 3)) << 4;
    const int aRd = wr * 8192 + p2 * 128 + (rb & 1) * 64 + swz;  // + m*1024; lo +16384
    const int bRd = wc * 4096 + p2 * 128 + (rb & 1) * 64 + swz;  // + n*1024; lo +16384

    if (tid < 256) scoreL[tid] = 0.f;

    f32x4 acc[8][4];
#pragma unroll
    for (int m = 0; m < 8; ++m)
#pragma unroll
        for (int n = 0; n < 4; ++n) acc[m][n] = (f32x4){0.f, 0.f, 0.f, 0.f};

    float4 pa0, pa1, pa2, pa3;   // raw A prefetch regs (2 rows x 8 f32)

#define A_LOAD(t) do { \
        const float* _p = aBase + (((t) & 31) << 5); \
        pa0 = ((const float4*)_p)[0]; \
        pa1 = ((const float4*)_p)[1]; \
        const float* _p2 = _p + 128 * 1024; \
        pa2 = ((const float4*)_p2)[0]; \
        pa3 = ((const float4*)_p2)[1]; \
    } while (0)
#define B_ISSUE_HI(t, buf) do { \
        const size_t _h = ((size_t)((t) >> 5) << 19) + (size_t)(((t) & 31)) * 64 + bD; \
        char* _b = smem + 65536 + (buf) * 32768; \
        gload_lds16(whiB + _h + (size_t)bRow0 * 2048,         _b + tid * 16); \
        gload_lds16(whiB + _h + (size_t)(bRow0 + 128) * 2048, _b + 8192 + tid * 16); \
    } while (0)
#define B_ISSUE_LO(t, buf) do { \
        const size_t _h = ((size_t)((t) >> 5) << 19) + (size_t)(((t) & 31)) * 64 + bD; \
        char* _b = smem + 65536 + (buf) * 32768 + 16384; \
        gload_lds16(wloB + _h + (size_t)bRow0 * 2048,         _b + tid * 16); \
        gload_lds16(wloB + _h + (size_t)(bRow0 + 128) * 2048, _b + 8192 + tid * 16); \
    } while (0)
#define A_STAGE(buf) do { \
        float _q[16] = {pa0.x, pa0.y, pa0.z, pa0.w, pa1.x, pa1.y, pa1.z, pa1.w, \
                        pa2.x, pa2.y, pa2.z, pa2.w, pa3.x, pa3.y, pa3.z, pa3.w}; \
        half8 _hi0, _lo0, _hi1, _lo1; \
        _Pragma("unroll") \
        for (int _j = 0; _j < 8; ++_j) { \
            _Float16 _h = (_Float16)_q[_j]; \
            _hi0[_j] = _h; \
            _lo0[_j] = (_Float16)(_q[_j] - (float)_h); \
            _Float16 _h2 = (_Float16)_q[_j + 8]; \
            _hi1[_j] = _h2; \
            _lo1[_j] = (_Float16)(_q[_j + 8] - (float)_h2); \
        } \
        char* _a = smem + (buf) * 32768; \
        *(half8*)(_a + aWofs)                 = _hi0; \
        *(half8*)(_a + 16384 + aWofs)         = _lo0; \
        *(half8*)(_a + 8192 + aWofs)          = _hi1; \
        *(half8*)(_a + 16384 + 8192 + aWofs)  = _lo1; \
    } while (0)
    // note: row+128 = +64 stripes = +8192 B; (p&3) unchanged so same chunk XOR.
#define LOAD_A_FRAG(rh, rl, m) do { \
        rh = *(const half8*)(sa + aRd + (m) * 1024); \
        rl = *(const half8*)(sa + 16384 + aRd + (m) * 1024); \
    } while (0)
#define MFMA_PAIR(mb) do { \
        _Pragma("unroll") \
        for (int n = 0; n < 4; ++n) { \
            acc[(mb)][n]   = __builtin_amdgcn_mfma_f32_16x16x32_f16(ah0, bh[n], acc[(mb)][n], 0, 0, 0); \
            acc[(mb)][n]   = __builtin_amdgcn_mfma_f32_16x16x32_f16(ah0, bl[n], acc[(mb)][n], 0, 0, 0); \
            acc[(mb)][n]   = __builtin_amdgcn_mfma_f32_16x16x32_f16(al0, bh[n], acc[(mb)][n], 0, 0, 0); \
            acc[(mb)+1][n] = __builtin_amdgcn_mfma_f32_16x16x32_f16(ah1, bh[n], acc[(mb)+1][n], 0, 0, 0); \
            acc[(mb)+1][n] = __builtin_amdgcn_mfma_f32_16x16x32_f16(ah1, bl[n], acc[(mb)+1][n], 0, 0, 0); \
            acc[(mb)+1][n] = __builtin_amdgcn_mfma_f32_16x16x32_f16(al1, bh[n], acc[(mb)+1][n], 0, 0, 0); \
        } \
    } while (0)
#define WAITLG0 do { asm volatile("s_waitcnt lgkmcnt(0)" ::: "memory"); \
                     __builtin_amdgcn_sched_barrier(0); } while (0)

    // ---- prologue: stage tile 0 into buf0, prime A pipeline (pa = tile 1) ----
    A_LOAD(0);
    B_ISSUE_HI(0, 0);
    B_ISSUE_LO(0, 0);
    A_STAGE(0);        // compiler waits its own raw loads, writes Abuf0
    A_LOAD(1);
    asm volatile("s_waitcnt vmcnt(0) lgkmcnt(0)" ::: "memory");
    __builtin_amdgcn_sched_barrier(0);
    __builtin_amdgcn_s_barrier();

    for (int t = 0; t < 128; ++t) {
        const int cur = t & 1;
        const char* sa = smem + cur * 32768;
        const char* sb = smem + 65536 + cur * 32768;
        half8 bh[4], bl[4];
        half8 ah0, al0, ah1, al1;

        // ======== P0: 12 ds_read (A m0,m1 + all B) | gload B-hi(t+1) ========
        LOAD_A_FRAG(ah0, al0, 0);
        LOAD_A_FRAG(ah1, al1, 1);
#pragma unroll
        for (int n = 0; n < 4; ++n) {
            bh[n] = *(const half8*)(sb + bRd + n * 1024);
            bl[n] = *(const half8*)(sb + 16384 + bRd + n * 1024);
        }
        if (t < 127) B_ISSUE_HI(t + 1, cur ^ 1);
        asm volatile("s_waitcnt lgkmcnt(8)" ::: "memory");
        __builtin_amdgcn_sched_barrier(0);
        __builtin_amdgcn_s_barrier();
        WAITLG0;
        __builtin_amdgcn_s_setprio(1);
        MFMA_PAIR(0);
        __builtin_amdgcn_s_setprio(0);
        __builtin_amdgcn_s_barrier();

        // ======== P1: 4 ds_read (A m2,m3) | gload B-lo(t+1) ========
        LOAD_A_FRAG(ah0, al0, 2);
        LOAD_A_FRAG(ah1, al1, 3);
        if (t < 127) B_ISSUE_LO(t + 1, cur ^ 1);
        __builtin_amdgcn_s_barrier();
        WAITLG0;
        __builtin_amdgcn_s_setprio(1);
        MFMA_PAIR(2);
        __builtin_amdgcn_s_setprio(0);
        __builtin_amdgcn_s_barrier();

        // ======== P2: 4 ds_read (A m4,m5) | convert+ds_write A(t+1) ========
        LOAD_A_FRAG(ah0, al0, 4);
        LOAD_A_FRAG(ah1, al1, 5);
        if (t < 127) A_STAGE(cur ^ 1);   // uses pa (tile t+1), 4 swizzled ds_write
        __builtin_amdgcn_s_barrier();
        WAITLG0;
        __builtin_amdgcn_s_setprio(1);
        MFMA_PAIR(4);
        __builtin_amdgcn_s_setprio(0);
        __builtin_amdgcn_s_barrier();

        // ======== P3: 4 ds_read (A m6,m7) | raw A loads(t+2) | vmcnt(4) ======
        LOAD_A_FRAG(ah0, al0, 6);
        LOAD_A_FRAG(ah1, al1, 7);
        if (t < 126) A_LOAD(t + 2);      // youngest vmem: stays in flight
        __builtin_amdgcn_s_barrier();
        if (t < 126) {
            asm volatile("s_waitcnt vmcnt(4) lgkmcnt(0)" ::: "memory");  // B(t+1) landed
        } else {
            asm volatile("s_waitcnt vmcnt(0) lgkmcnt(0)" ::: "memory");  // tail drain
        }
        __builtin_amdgcn_sched_barrier(0);
        __builtin_amdgcn_s_setprio(1);
        MFMA_PAIR(6);
        __builtin_amdgcn_s_setprio(0);

        if ((t & 31) == 31) {
            // epilogue for hc = t>>5: branch-free tanh + w_out, reduce, atomic
            const int h0 = (t >> 5) << 8;
#pragma unroll
            for (int m = 0; m < 8; ++m) {
                float con[4] = {0.f, 0.f, 0.f, 0.f};
#pragma unroll
                for (int n = 0; n < 4; ++n) {
                    int h = h0 + wc * 64 + n * 16 + rb;
                    float dwv = dwb[h];
                    float wo  = w_out[h];
#pragma unroll
                    for (int r = 0; r < 4; ++r) {
                        float x = acc[m][n][r] + dwv;
                        float e = __expf(2.0f * fabsf(x));
                        float th = copysignf(1.0f - __fdividef(2.0f, e + 1.0f), x);
                        con[r] += th * wo;
                    }
                    acc[m][n] = (f32x4){0.f, 0.f, 0.f, 0.f};
                }
#pragma unroll
                for (int r = 0; r < 4; ++r) {
                    float v = con[r];
                    v += __shfl_xor(v, 1);
                    v += __shfl_xor(v, 2);
                    v += __shfl_xor(v, 4);
                    v += __shfl_xor(v, 8);
                    con[r] = v;
                }
                if (rb == 0) {
                    int rbase = wr * 128 + m * 16 + ksl * 4;
#pragma unroll
                    for (int r = 0; r < 4; ++r)
                        atomicAdd(&scoreL[rbase + r], con[r]);
                }
            }
        }
        __builtin_amdgcn_s_barrier();
    }

    __syncthreads();
    if (tid < 256) scores[m0 + tid] = scoreL[tid];
#undef A_LOAD
#undef B_ISSUE_HI
#undef B_ISSUE_LO
#undef A_STAGE
#undef LOAD_A_FRAG
#undef MFMA_PAIR
#undef WAITLG0
}

// ---------------- kernel 3: masked softmax over N per batch ----------------
// mask is bool in python -> pushed as int32.
__global__ void k_softmax(const float* __restrict__ scores,
                          const int* __restrict__ mask,
                          float* __restrict__ probs, float* __restrict__ out_probs) {
    int b = blockIdx.x, tid = threadIdx.x;
    __shared__ float red[8];
    float v[8];
    float m = -INFINITY;
#pragma unroll
    for (int i = 0; i < 8; ++i) {
        int n = tid + i * 256;
        float s = scores[b * 2048 + n];
        s = (mask[b * 2048 + n] != 0) ? s : -INFINITY;
        v[i] = s;
        m = fmaxf(m, s);
    }
    for (int off = 32; off; off >>= 1) m = fmaxf(m, __shfl_xor(m, off));
    if ((tid & 63) == 0) red[tid >> 6] = m;
    __syncthreads();
    m = fmaxf(fmaxf(red[0], red[1]), fmaxf(red[2], red[3]));
    float sum = 0.f;
#pragma unroll
    for (int i = 0; i < 8; ++i) {
        v[i] = expf(v[i] - m);
        sum += v[i];
    }
    for (int off = 32; off; off >>= 1) sum += __shfl_xor(sum, off);
    if ((tid & 63) == 0) red[4 + (tid >> 6)] = sum;
    __syncthreads();
    sum = red[4] + red[5] + red[6] + red[7];
    float inv = 1.0f / sum;
#pragma unroll
    for (int i = 0; i < 8; ++i) {
        int n = tid + i * 256;
        float p = v[i] * inv;
        probs[b * 2048 + n]     = p;
        out_probs[b * 2048 + n] = p;
    }
}

// ---------------- kernel 4: attn[b,e] += sum_n probs[b,n]*enc[b,n,e] --------
// Survivor compaction (softmax is near-one-hot), then unconditional FMA loop.
__global__ void k_attn(const float* __restrict__ probs, const float* __restrict__ enc,
                       float* __restrict__ attn) {
    __shared__ float pv[128];
    __shared__ int   pidx[128];
    __shared__ int   cnt;
    int b = blockIdx.x, c = blockIdx.y, t = threadIdx.x;
    if (t == 0) cnt = 0;
    __syncthreads();
    if (t < 128) {
        float p = probs[b * 2048 + c * 128 + t];
        if (p >= 1e-12f) {
            int slot = atomicAdd(&cnt, 1);
            pv[slot]   = p;
            pidx[slot] = c * 128 + t;
        }
    }
    __syncthreads();
    int nk = cnt;
    if (nk == 0) return;
    const float* eb = enc + (size_t)b * 2048 * 1024;
    float4 acc = {0.f, 0.f, 0.f, 0.f};
    for (int i = 0; i < nk; ++i) {
        float p = pv[i];
        float4 v = ((const float4*)(eb + (size_t)pidx[i] * 1024))[t];
        acc.x += p * v.x;
        acc.y += p * v.y;
        acc.z += p * v.z;
        acc.w += p * v.w;
    }
    float* o = attn + b * 1024 + t * 4;
    atomicAdd(o + 0, acc.x);
    atomicAdd(o + 1, acc.y);
    atomicAdd(o + 2, acc.z);
    atomicAdd(o + 3, acc.w);
}

extern "C" void kernel_launch(void* const* d_in, const int* in_sizes, int n_in,
                              void* d_out, int out_size, void* d_ws, size_t ws_size,
                              hipStream_t stream) {
    const float* enc   = (const float*)d_in[0];  // [32,2048,1024]
    const float* dec   = (const float*)d_in[1];  // [32,1024]
    const int*   mask  = (const int*)d_in[2];    // [32,2048] bool -> int32
    const float* w_e   = (const float*)d_in[3];  // [1024,1024]
    const float* w_d   = (const float*)d_in[4];  // [1024,1024]
    const float* w_out = (const float*)d_in[5];  // [1024]

    float* out_attn  = (float*)d_out;              // [32*1024]
    float* out_probs = out_attn + Bsz * Hdim;      // [32*2048]

    float* dw        = (float*)d_ws;               // 32*1024
    float* scores    = dw + Bsz * Hdim;            // 32*2048
    float* probs     = scores + Bsz * Nseq;        // 32*2048
    _Float16* w_hiT  = (_Float16*)(probs + Bsz * Nseq);  // [1024*1024]
    _Float16* w_loT  = w_hiT + Edim * Hdim;

    static const int kScoresLds = 132096;   // 128 KB bufs + 1 KB scoreL
    hipFuncSetAttribute((const void*)k_scores,
                        hipFuncAttributeMaxDynamicSharedMemorySize, kScoresLds);

    hipMemsetAsync(out_attn, 0, Bsz * Hdim * sizeof(float), stream);
    k_dw<<<dim3(32, 4), dim3(256), 0, stream>>>(dec, w_d, dw);
    k_split<<<dim3(32, 32), dim3(256), 0, stream>>>(w_e, w_hiT, w_loT);
    k_scores<<<dim3(256), dim3(512), kScoresLds, stream>>>(enc, w_hiT, w_loT, dw, w_out, scores);
    k_softmax<<<dim3(32), dim3(256), 0, stream>>>(scores, mask, probs, out_probs);
    k_attn<<<dim3(32, 16), dim3(256), 0, stream>>>(probs, enc, out_attn);
}